// Round 6
// baseline (471.585 us; speedup 1.0000x reference)
//
#include <hip/hip_runtime.h>
#include <math.h>

// ---------------------------------------------------------------------------
// VQ-VAE forward, bf16-MFMA version (R6 = R5 with deconv2 grid fix: 32 bands).
//   conv1 (fp32 VALU) -> z1T [n][128][128][64c] bf16
//   conv2 (MFMA)      -> ze  [n][64c][64][64]   bf16 (NCHW)
//   vq    (MFMA)      -> zq  fp32 d_out (exact cb rows) + zqT [n][64][64][64c] bf16
//   deconv1 (MFMA)    -> hT  [n][128][128][64c] bf16 (aliases z1T)
//   deconv2 (MFMA)    -> xr  fp32 d_out (wide-band: 8 rows x 256 cols / block)
// ---------------------------------------------------------------------------

typedef __attribute__((ext_vector_type(8))) short short8;
typedef __attribute__((ext_vector_type(4))) short short4v;
typedef __attribute__((ext_vector_type(4))) float f32x4;

#define MFMA16(a, b, c) __builtin_amdgcn_mfma_f32_16x16x32_bf16((a), (b), (c), 0, 0, 0)

__device__ __forceinline__ short f2bf(float f) {
  union { float f; unsigned u; } x; x.f = f;
  unsigned r = (x.u + 0x7FFFu + ((x.u >> 16) & 1u)) >> 16;
  return (short)r;
}
__device__ __forceinline__ float bf2f(short s) {
  union { unsigned u; float f; } x;
  x.u = ((unsigned)(unsigned short)s) << 16;
  return x.f;
}

// ------------------------------ prep ---------------------------------------
__global__ __launch_bounds__(256) void k_prep(const float* __restrict__ w2,
                                              const float* __restrict__ dw1,
                                              const float* __restrict__ dw2,
                                              const float* __restrict__ cb,
                                              short* __restrict__ A2,
                                              short* __restrict__ AD1,
                                              short* __restrict__ AD2,
                                              short* __restrict__ cbb,
                                              float* __restrict__ cnm) {
  int i = blockIdx.x * 256 + threadIdx.x;  // 0..65535
  {
    int t = i >> 12, oc = (i >> 6) & 63, c = i & 63;
    A2[i] = f2bf(w2[(oc * 64 + c) * 16 + t]);
  }
  {
    int p = i >> 14, ab = (i >> 12) & 3, oc = (i >> 6) & 63, c = i & 63;
    int kh = 1 - (p >> 1) + 2 * (ab >> 1);
    int kw = 1 - (p & 1) + 2 * (ab & 1);
    AD1[i] = f2bf(dw1[(c * 64 + oc) * 16 + kh * 4 + kw]);
  }
  if (i < 16384) {
    int p = i >> 12, ab = (i >> 10) & 3, oc = (i >> 6) & 15, c = i & 63;
    int kh = 1 - (p >> 1) + 2 * (ab >> 1);
    int kw = 1 - (p & 1) + 2 * (ab & 1);
    short v = 0;
    if (oc < 3) v = f2bf(dw2[(c * 3 + oc) * 16 + kh * 4 + kw]);
    AD2[i] = v;
  }
  if (i < 32768) cbb[i] = f2bf(cb[i]);
  if (i < 512) {
    float s = 0.f;
    for (int d = 0; d < 64; ++d) { float v = cb[i * 64 + d]; s += v * v; }
    cnm[i] = s;
  }
}

// ------------------------------ conv1 --------------------------------------
__global__ __launch_bounds__(256) void k_conv1(const float* __restrict__ x,
                                               const float* __restrict__ w1,
                                               const float* __restrict__ b1,
                                               short* __restrict__ z1T) {
  __shared__ float sW[3 * 16 * 64];
  __shared__ float sB[64];
  __shared__ float sIn[3 * 34 * 34];
  __shared__ short sOutC[256 * 72];
  const int tid = threadIdx.x;

  {
    float tw[12];
#pragma unroll
    for (int it = 0; it < 12; ++it) {
      int i = tid + 256 * it;
      int oc = i & 63, t = (i >> 6) & 15, c = i >> 10;
      tw[it] = w1[(oc * 3 + c) * 16 + t];
    }
#pragma unroll
    for (int it = 0; it < 12; ++it) sW[tid + 256 * it] = tw[it];
  }
  if (tid < 64) sB[tid] = b1[tid];

  const int b = blockIdx.x;
  const int n = b >> 6;
  const int tile = b & 63;
  const int tr = tile >> 3, tc = tile & 7;
  const int oh0 = tr * 16, ow0 = tc * 16;
  const int ih_base = oh0 * 2 - 1, iw_base = ow0 * 2 - 1;

  {
    float t[14]; bool vd[14];
#pragma unroll
    for (int it = 0; it < 14; ++it) {
      int i = tid + 256 * it;
      vd[it] = i < 3468;
      int ii = vd[it] ? i : 0;
      int c = ii / 1156;
      int rem = ii - c * 1156;
      int r = rem / 34;
      int col = rem - r * 34;
      int ih = ih_base + r, iw = iw_base + col;
      float v = 0.f;
      if (vd[it] && (unsigned)ih < 256u && (unsigned)iw < 256u)
        v = x[((n * 3 + c) * 256 + ih) * 256 + iw];
      t[it] = v;
    }
#pragma unroll
    for (int it = 0; it < 14; ++it)
      if (vd[it]) sIn[tid + 256 * it] = t[it];
  }
  __syncthreads();

  const int ty = tid >> 4, tx = tid & 15;
  float acc[64];
#pragma unroll
  for (int j = 0; j < 64; ++j) acc[j] = sB[j];

  for (int c = 0; c < 3; ++c) {
    for (int t = 0; t < 16; ++t) {
      int kh = t >> 2, kw = t & 3;
      float v = sIn[c * 1156 + (2 * ty + kh) * 34 + (2 * tx + kw)];
      const float4* wp = (const float4*)&sW[(c * 16 + t) * 64];
#pragma unroll
      for (int j = 0; j < 16; ++j) {
        float4 w4 = wp[j];
        acc[4 * j + 0] += v * w4.x;
        acc[4 * j + 1] += v * w4.y;
        acc[4 * j + 2] += v * w4.z;
        acc[4 * j + 3] += v * w4.w;
      }
    }
  }

  const int sp = ty * 16 + tx;
#pragma unroll
  for (int kk = 0; kk < 8; ++kk) {
    short8 v;
#pragma unroll
    for (int t2 = 0; t2 < 8; ++t2) {
      float r = acc[8 * kk + t2];
      v[t2] = f2bf(r > 0.f ? r : 0.f);
    }
    *(short8*)&sOutC[sp * 72 + 8 * kk] = v;
  }
  __syncthreads();
  const int r = tid >> 4, jj = tid & 15;
#pragma unroll
  for (int it = 0; it < 8; ++it) {
    int chunk = jj + 16 * it;
    int owL = chunk >> 3, c8 = chunk & 7;
    short8 v = *(const short8*)&sOutC[(r * 16 + owL) * 72 + 8 * c8];
    *(short8*)(z1T + (((long)(n * 128 + oh0 + r) * 128) + ow0 + owL) * 64 + 8 * c8) = v;
  }
}

// ------------------------------ conv2 (MFMA) -------------------------------
__global__ __launch_bounds__(256) void k_conv2(const short* __restrict__ z1T,
                                               const short* __restrict__ A2,
                                               const float* __restrict__ b2,
                                               short* __restrict__ ze) {
  __shared__ char smemC[62400];
  __shared__ float sB2c[64];
  short* slab = (short*)smemC;
  short* sOut = (short*)smemC;

  const int tid = threadIdx.x;
  if (tid < 64) sB2c[tid] = b2[tid];
  const int b = blockIdx.x;
  const int n = b >> 5;
  const int oh0 = (b & 31) * 2;
  const int w = tid >> 6, l = tid & 63;
  const int row = w >> 1, mh = w & 1;
  const int e = l & 15, kg = l >> 4;
  const int ih0 = 2 * oh0 - 1;

  f32x4 acc[2][4];
#pragma unroll
  for (int mi = 0; mi < 2; ++mi)
#pragma unroll
    for (int nt = 0; nt < 4; ++nt) acc[mi][nt] = (f32x4){0.f, 0.f, 0.f, 0.f};

  for (int p = 0; p < 2; ++p) {
    const int c0 = 32 * p;
    __syncthreads();
    {
      short8 ta[7]; int off[7];
#pragma unroll
      for (int it = 0; it < 7; ++it) {
        int i = tid + 256 * it;
        int r = i / 520;
        int rem = i - r * 520;
        int iwL = rem >> 2, li = rem & 3;
        int ih = ih0 + r, iw = iwL - 1;
        off[it] = 8 * ((r * 130 + iwL) * 5 + li);
        short8 v = {0, 0, 0, 0, 0, 0, 0, 0};
        if ((unsigned)ih < 128u && (unsigned)iw < 128u)
          v = *(const short8*)(z1T + (((long)(n * 128 + ih) * 128) + iw) * 64 + c0 + 8 * li);
        ta[it] = v;
      }
#pragma unroll
      for (int it = 0; it < 7; ++it) *(short8*)&slab[off[it]] = ta[it];
    }
    {
      short8 tb[6]; int off[6]; bool vd[6];
#pragma unroll
      for (int it = 0; it < 6; ++it) {
        int i = tid + 256 * (7 + it);
        vd[it] = i < 3120;
        int ii = vd[it] ? i : 0;
        int r = ii / 520;
        int rem = ii - r * 520;
        int iwL = rem >> 2, li = rem & 3;
        int ih = ih0 + r, iw = iwL - 1;
        off[it] = 8 * ((r * 130 + iwL) * 5 + li);
        short8 v = {0, 0, 0, 0, 0, 0, 0, 0};
        if (vd[it] && (unsigned)ih < 128u && (unsigned)iw < 128u)
          v = *(const short8*)(z1T + (((long)(n * 128 + ih) * 128) + iw) * 64 + c0 + 8 * li);
        tb[it] = v;
      }
#pragma unroll
      for (int it = 0; it < 6; ++it)
        if (vd[it]) *(short8*)&slab[off[it]] = tb[it];
    }
    __syncthreads();

    for (int t = 0; t < 16; ++t) {
      const int kh = t >> 2, kw = t & 3;
      const int rL = 2 * row + kh;
      short8 aF[2], bF[4];
#pragma unroll
      for (int mi = 0; mi < 2; ++mi)
        aF[mi] = *(const short8*)(A2 + ((t * 64 + 32 * mh + 16 * mi + e) * 64) + c0 + 8 * kg);
#pragma unroll
      for (int nt = 0; nt < 4; ++nt) {
        int iwL = 2 * (nt * 16 + e) + kw;
        bF[nt] = *(const short8*)&slab[8 * ((rL * 130 + iwL) * 5 + kg)];
      }
#pragma unroll
      for (int mi = 0; mi < 2; ++mi)
#pragma unroll
        for (int nt = 0; nt < 4; ++nt)
          acc[mi][nt] = MFMA16(aF[mi], bF[nt], acc[mi][nt]);
    }
  }

  __syncthreads();
#pragma unroll
  for (int mi = 0; mi < 2; ++mi)
#pragma unroll
    for (int nt = 0; nt < 4; ++nt)
#pragma unroll
      for (int rr = 0; rr < 4; ++rr) {
        int oc = 32 * mh + 16 * mi + 4 * kg + rr;
        float v = acc[mi][nt][rr] + sB2c[oc];
        sOut[(row * 64 + oc) * 68 + nt * 16 + e] = f2bf(v > 0.f ? v : 0.f);
      }
  __syncthreads();
  {
    int oc = 32 * mh + (l >> 1);
    int half = l & 1;
#pragma unroll
    for (int j = 0; j < 8; ++j) {
      short4v v = *(const short4v*)&sOut[(row * 64 + oc) * 68 + 32 * half + 4 * j];
      *(short4v*)(ze + (((long)(n * 64 + oc) * 64) + oh0 + row) * 64 + 32 * half + 4 * j) = v;
    }
  }
}

// ------------------------------ vq (MFMA) ----------------------------------
// block: (n,h). zqT written via LDS [w][c] transpose -> coalesced short8 stores.
__global__ __launch_bounds__(256) void k_vq(const short* __restrict__ zeb,
                                            const short* __restrict__ cbb,
                                            const float* __restrict__ cnm,
                                            const float* __restrict__ cb,
                                            float* __restrict__ zq,
                                            short* __restrict__ zqT) {
  __shared__ short sT[64 * 68];   // [w][c+pad]
  const int tid = threadIdx.x;
  const int wv = tid >> 6, l = tid & 63;
  const int e = l & 15, kg = l >> 4;
  const int b = blockIdx.x;
  const int n = b >> 6, h = b & 63;

  const short* zebase = zeb + (((long)(n * 64 + 16 * wv + e) * 64) + h) * 64;
  short8 aF0 = *(const short8*)(zebase + 8 * kg);
  short8 aF1 = *(const short8*)(zebase + 32 + 8 * kg);

  float bestD[4];
  int bestI[4];
#pragma unroll
  for (int rr = 0; rr < 4; ++rr) { bestD[rr] = 3.4e38f; bestI[rr] = 0; }

  for (int ch = 0; ch < 8; ++ch) {
    f32x4 acc[4];
#pragma unroll
    for (int nt = 0; nt < 4; ++nt) {
      acc[nt] = (f32x4){0.f, 0.f, 0.f, 0.f};
      const short* cbase = cbb + (ch * 64 + nt * 16 + e) * 64;
      short8 b0 = *(const short8*)(cbase + 8 * kg);
      short8 b1 = *(const short8*)(cbase + 32 + 8 * kg);
      acc[nt] = MFMA16(aF0, b0, acc[nt]);
      acc[nt] = MFMA16(aF1, b1, acc[nt]);
    }
#pragma unroll
    for (int nt = 0; nt < 4; ++nt) {
      int code = ch * 64 + nt * 16 + e;
      float cn = cnm[code];
#pragma unroll
      for (int rr = 0; rr < 4; ++rr) {
        float d = cn - 2.f * acc[nt][rr];
        if (d < bestD[rr]) { bestD[rr] = d; bestI[rr] = code; }
      }
    }
  }
#pragma unroll
  for (int m = 1; m <= 8; m <<= 1) {
#pragma unroll
    for (int rr = 0; rr < 4; ++rr) {
      float od = __shfl_xor(bestD[rr], m);
      int oi = __shfl_xor(bestI[rr], m);
      if (od < bestD[rr] || (od == bestD[rr] && oi < bestI[rr])) {
        bestD[rr] = od; bestI[rr] = oi;
      }
    }
  }
  // zq fp32 write (exact codebook rows) + LDS transpose for zqT
#pragma unroll
  for (int rr = 0; rr < 4; ++rr) {
    int c = 16 * wv + 4 * kg + rr;
    int idx = bestI[rr];
    float4 v = *(const float4*)(cb + idx * 64 + 4 * e);
    *(float4*)(zq + (((long)(n * 64 + c) * 64) + h) * 64 + 4 * e) = v;
    sT[(4 * e + 0) * 68 + c] = f2bf(v.x);
    sT[(4 * e + 1) * 68 + c] = f2bf(v.y);
    sT[(4 * e + 2) * 68 + c] = f2bf(v.z);
    sT[(4 * e + 3) * 68 + c] = f2bf(v.w);
  }
  __syncthreads();
  {
    int wq = tid >> 2, hq = tid & 3;       // w row, 16c-chunk
    short8 v0 = *(const short8*)&sT[wq * 68 + 16 * hq];
    short8 v1 = *(const short8*)&sT[wq * 68 + 16 * hq + 8];
    short* dst = zqT + (((long)(n * 64 + h) * 64) + wq) * 64 + 16 * hq;
    *(short8*)dst = v0;
    *(short8*)(dst + 8) = v1;
  }
}

// ------------------------------ deconv1 (MFMA, parity) ---------------------
__global__ __launch_bounds__(256) void k_deconv1(const short* __restrict__ zqT,
                                                 const short* __restrict__ AD1,
                                                 const float* __restrict__ db1,
                                                 short* __restrict__ hT) {
  __shared__ char smemD[34816];
  __shared__ float sBias[64];
  short* slab = (short*)smemD;
  short* sOut = (short*)smemD;

  const int tid = threadIdx.x;
  if (tid < 64) sBias[tid] = db1[tid];
  const int b = blockIdx.x;
  const int n = b >> 6, i0 = b & 63;
  const int w = tid >> 6, l = tid & 63;
  const int ph = w >> 1, pw = w & 1;
  const int e = l & 15, kg = l >> 4;

  {
    short8 t[7]; int off[7]; bool vd[7];
#pragma unroll
    for (int it = 0; it < 7; ++it) {
      int i = tid + 256 * it;
      vd[it] = i < 1584;
      int ii = vd[it] ? i : 0;
      int r = ii / 528;
      int rem = ii - r * 528;
      int iwL = rem >> 3, li = rem & 7;
      int ih = i0 - 1 + r, iw = iwL - 1;
      off[it] = (r * 66 + iwL) * 72 + 8 * li;
      short8 v = {0, 0, 0, 0, 0, 0, 0, 0};
      if (vd[it] && (unsigned)ih < 64u && (unsigned)iw < 64u)
        v = *(const short8*)(zqT + (((long)(n * 64 + ih) * 64) + iw) * 64 + 8 * li);
      t[it] = v;
    }
#pragma unroll
    for (int it = 0; it < 7; ++it)
      if (vd[it]) *(short8*)&slab[off[it]] = t[it];
  }
  __syncthreads();

  f32x4 acc[4][4];
#pragma unroll
  for (int m = 0; m < 4; ++m)
#pragma unroll
    for (int nt = 0; nt < 4; ++nt) acc[m][nt] = (f32x4){0.f, 0.f, 0.f, 0.f};

  for (int ab = 0; ab < 4; ++ab) {
    const int rL = 1 + ph - (ab >> 1);
    const int coff = pw - (ab & 1) + 1;
#pragma unroll
    for (int ks = 0; ks < 2; ++ks) {
      short8 aF[4], bF[4];
#pragma unroll
      for (int m = 0; m < 4; ++m)
        aF[m] = *(const short8*)(AD1 + (((w * 4 + ab) * 64 + 16 * m + e) * 64) + 32 * ks + 8 * kg);
#pragma unroll
      for (int nt = 0; nt < 4; ++nt) {
        int iwL = nt * 16 + e + coff;
        bF[nt] = *(const short8*)&slab[(rL * 66 + iwL) * 72 + 32 * ks + 8 * kg];
      }
#pragma unroll
      for (int m = 0; m < 4; ++m)
#pragma unroll
        for (int nt = 0; nt < 4; ++nt)
          acc[m][nt] = MFMA16(aF[m], bF[nt], acc[m][nt]);
    }
  }

  __syncthreads();
#pragma unroll
  for (int m = 0; m < 4; ++m)
#pragma unroll
    for (int nt = 0; nt < 4; ++nt) {
      int owIdx = nt * 16 + e;
      int oc0 = 16 * m + 4 * kg;
      short4v o;
#pragma unroll
      for (int rr = 0; rr < 4; ++rr) {
        float v = acc[m][nt][rr] + sBias[oc0 + rr];
        o[rr] = f2bf(v > 0.f ? v : 0.f);
      }
      *(short4v*)&sOut[((w * 64 + owIdx) * 68) + oc0] = o;
    }
  __syncthreads();
  {
    const int oh = 2 * i0 + ph;
    const int ow = 2 * l + pw;
    short* dst = hT + (((long)(n * 128 + oh) * 128) + ow) * 64;
#pragma unroll
    for (int j = 0; j < 16; ++j) {
      short4v v = *(const short4v*)&sOut[((w * 64 + l) * 68) + 4 * j];
      *(short4v*)(dst + 4 * j) = v;
    }
  }
}

// ------------------------------ deconv2 (MFMA, wide-band) ------------------
// block: (n, band), band 0..31. outputs oh = 8*band..8*band+7, full 256 width.
// 512 threads = 8 waves: w = ph*4 + pw*2 + chf. Wave computes parity (ph,pw),
// cols owIdx in [64*chf, 64*chf+63], rows j=0..3 (oh = 8band+2j+ph).
// K split: 2 passes x 32c; slab [6][130][36-pad] bf16 single-buffered,
// pass-1 loads issued before pass-0 MFMA. sOut [3][8][256] f32 aliases slab.
__global__ __launch_bounds__(512) void k_deconv2(const short* __restrict__ hT,
                                                 const short* __restrict__ AD2,
                                                 const float* __restrict__ db2,
                                                 float* __restrict__ xr) {
  __shared__ __align__(16) char smem[56160];   // slab 6*130*36*2 B
  __shared__ float sB2[3];
  short* slab = (short*)smem;
  float* sOut = (float*)smem;                  // [3][8][256] f32 = 24576 B

  const int tid = threadIdx.x;
  if (tid < 3) sB2[tid] = db2[tid];
  const int b = blockIdx.x;
  const int n = b >> 5;                        // 32 bands per image
  const int band = b & 31;
  const int w = tid >> 6, l = tid & 63;
  const int ph = w >> 2, pw = (w >> 1) & 1, chf = w & 1;
  const int p = ph * 2 + pw;
  const int e = l & 15, kg = l >> 4;

  // staging decode: 3120 lines (6r x 130iw x 4li), 512 thr -> <=7 each
  int soff[7]; long sga[7]; bool sv[7], sinb[7];
#pragma unroll
  for (int it = 0; it < 7; ++it) {
    int i = tid + 512 * it;
    sv[it] = i < 3120;
    int ii = sv[it] ? i : 0;
    int r = ii / 520;
    int rm = ii - r * 520;
    int iwL = rm >> 2, li = rm & 3;
    int ih = 4 * band - 1 + r, iw = iwL - 1;
    sinb[it] = sv[it] && (unsigned)ih < 128u && (unsigned)iw < 128u;
    soff[it] = (r * 130 + iwL) * 36 + 8 * li;
    sga[it] = (((long)(n * 128 + ih) * 128) + iw) * 64 + 8 * li;
  }

  // ---- stage pass 0 (c 0..31)
  {
    short8 t0[7];
#pragma unroll
    for (int it = 0; it < 7; ++it) {
      short8 v = {0, 0, 0, 0, 0, 0, 0, 0};
      if (sinb[it]) v = *(const short8*)(hT + sga[it]);
      t0[it] = v;
    }
#pragma unroll
    for (int it = 0; it < 7; ++it)
      if (sv[it]) *(short8*)&slab[soff[it]] = t0[it];
  }
  __syncthreads();

  // ---- issue pass-1 loads (c 32..63)
  short8 t1[7];
#pragma unroll
  for (int it = 0; it < 7; ++it) {
    short8 v = {0, 0, 0, 0, 0, 0, 0, 0};
    if (sinb[it]) v = *(const short8*)(hT + sga[it] + 32);
    t1[it] = v;
  }

  f32x4 acc[4][4];   // [j][nt]
#pragma unroll
  for (int j = 0; j < 4; ++j)
#pragma unroll
    for (int nt = 0; nt < 4; ++nt) acc[j][nt] = (f32x4){0.f, 0.f, 0.f, 0.f};

  const int colBase = 64 * chf + e + pw + 1;   // iwL = nt*16 + colBase - bb
  // ---- pass 0 MFMA
  {
    short8 aF[4];
#pragma unroll
    for (int ab = 0; ab < 4; ++ab)
      aF[ab] = *(const short8*)(AD2 + (((p * 4 + ab) * 16 + e) * 64) + 8 * kg);
#pragma unroll
    for (int ab = 0; ab < 4; ++ab) {
      const int a = ab >> 1, bb = ab & 1;
#pragma unroll
      for (int j = 0; j < 4; ++j) {
        const int rL = j + ph - a + 1;
#pragma unroll
        for (int nt = 0; nt < 4; ++nt) {
          const int iwL = nt * 16 + colBase - bb;
          short8 bf = *(const short8*)&slab[(rL * 130 + iwL) * 36 + 8 * kg];
          acc[j][nt] = MFMA16(aF[ab], bf, acc[j][nt]);
        }
      }
    }
  }
  __syncthreads();   // all waves done reading pass-0 slab

  // ---- write pass-1, barrier, pass-1 MFMA
#pragma unroll
  for (int it = 0; it < 7; ++it)
    if (sv[it]) *(short8*)&slab[soff[it]] = t1[it];
  __syncthreads();
  {
    short8 aF[4];
#pragma unroll
    for (int ab = 0; ab < 4; ++ab)
      aF[ab] = *(const short8*)(AD2 + (((p * 4 + ab) * 16 + e) * 64) + 32 + 8 * kg);
#pragma unroll
    for (int ab = 0; ab < 4; ++ab) {
      const int a = ab >> 1, bb = ab & 1;
#pragma unroll
      for (int j = 0; j < 4; ++j) {
        const int rL = j + ph - a + 1;
#pragma unroll
        for (int nt = 0; nt < 4; ++nt) {
          const int iwL = nt * 16 + colBase - bb;
          short8 bf = *(const short8*)&slab[(rL * 130 + iwL) * 36 + 8 * kg];
          acc[j][nt] = MFMA16(aF[ab], bf, acc[j][nt]);
        }
      }
    }
  }
  __syncthreads();   // done reading slab before sOut alias write

  // ---- epilogue: sigmoid on kg==0 lanes
  if (kg == 0) {
#pragma unroll
    for (int j = 0; j < 4; ++j)
#pragma unroll
      for (int nt = 0; nt < 4; ++nt) {
        int ohl = 2 * j + ph;
        int ow = 2 * (64 * chf + nt * 16 + e) + pw;
#pragma unroll
        for (int rr = 0; rr < 3; ++rr) {
          float v = 1.f / (1.f + expf(-(acc[j][nt][rr] + sB2[rr])));
          sOut[(rr * 8 + ohl) * 256 + ow] = v;
        }
      }
  }
  __syncthreads();
  // ---- coalesced store: 1536 float4, 512 thr -> 3 each
#pragma unroll
  for (int it = 0; it < 3; ++it) {
    int i = tid + 512 * it;
    int oc = i / 512, rem = i - oc * 512;
    int ohl = rem >> 6, c4 = rem & 63;
    float4 v = ((const float4*)sOut)[i];
    *(float4*)(xr + (((long)(n * 3 + oc) * 256) + 8 * band + ohl) * 256 + 4 * c4) = v;
  }
}

// ------------------------------ launch -------------------------------------
extern "C" void kernel_launch(void* const* d_in, const int* in_sizes, int n_in,
                              void* d_out, int out_size, void* d_ws, size_t ws_size,
                              hipStream_t stream) {
  (void)in_sizes; (void)n_in; (void)out_size; (void)ws_size;

  const float* x   = (const float*)d_in[0];
  const float* w1  = (const float*)d_in[1];
  const float* b1  = (const float*)d_in[2];
  const float* w2  = (const float*)d_in[3];
  const float* b2  = (const float*)d_in[4];
  const float* cb  = (const float*)d_in[5];
  const float* dw1 = (const float*)d_in[6];
  const float* db1 = (const float*)d_in[7];
  const float* dw2 = (const float*)d_in[8];
  const float* db2 = (const float*)d_in[9];

  char* wsb = (char*)d_ws;
  short* z1T = (short*)wsb;                        // 67,108,864 B (also hT)
  short* zeb = (short*)(wsb + 67108864);           // 16,777,216 B
  short* zqT = (short*)(wsb + 83886080);           // 16,777,216 B
  short* A2  = (short*)(wsb + 100663296);          //    131,072 B
  short* AD1 = (short*)(wsb + 100794368);          //    131,072 B
  short* cbb = (short*)(wsb + 100925440);          //     65,536 B
  float* cnm = (float*)(wsb + 100990976);          //      2,048 B
  short* AD2 = (short*)(wsb + 100993024);          //     32,768 B
  short* hT  = z1T;                                // alias (z1T dead after conv2)

  float* xr = (float*)d_out;                       // 6,291,456 f32
  float* zq = (float*)d_out + 6291456;             // 8,388,608 f32

  k_prep<<<256, 256, 0, stream>>>(w2, dw1, dw2, cb, A2, AD1, AD2, cbb, cnm);
  k_conv1<<<2048, 256, 0, stream>>>(x, w1, b1, z1T);
  k_conv2<<<1024, 256, 0, stream>>>(z1T, A2, b2, zeb);
  k_vq<<<2048, 256, 0, stream>>>(zeb, cbb, cnm, cb, zq, zqT);
  k_deconv1<<<2048, 256, 0, stream>>>(zqT, AD1, db1, hT);
  k_deconv2<<<1024, 512, 0, stream>>>(hT, AD2, db2, xr);
}